// Round 9
// baseline (428.885 us; speedup 1.0000x reference)
//
#include <hip/hip_runtime.h>
#include <math.h>
#include <float.h>

#define NN 20000
#define EE 320000
#define INDIM 16
#define HID 50
#define TW 5
#define FO 10
#define NGROUPS 64
#define NBINS 64
#define NBLK 2556   // (NN + NBINS*7)/8 rounded up

typedef float f4 __attribute__((ext_vector_type(4)));
typedef float f2 __attribute__((ext_vector_type(2)));

__device__ inline f4 f4_min(f4 a, f4 b) {
    f4 r; r.x = fminf(a.x, b.x); r.y = fminf(a.y, b.y);
    r.z = fminf(a.z, b.z); r.w = fminf(a.w, b.w); return r;
}
__device__ inline f4 f4_max(f4 a, f4 b) {
    f4 r; r.x = fmaxf(a.x, b.x); r.y = fmaxf(a.y, b.y);
    r.z = fmaxf(a.z, b.z); r.w = fmaxf(a.w, b.w); return r;
}
__device__ inline float sh3sum(float v, int g0, int G_) {
    return v + __shfl(v, g0 + G_, 64) + __shfl(v, g0 + 2 * G_, 64);
}
__device__ inline float sh3min(float v, int g0, int G_) {
    return fminf(fminf(v, __shfl(v, g0 + G_, 64)), __shfl(v, g0 + 2 * G_, 64));
}
__device__ inline float sh3max(float v, int g0, int G_) {
    return fmaxf(fmaxf(v, __shfl(v, g0 + G_, 64)), __shfl(v, g0 + 2 * G_, 64));
}
__device__ inline void acc4(float& acc, f4 w, float a0, float a1, float a2, float a3) {
    acc += w.x * a0; acc += w.y * a1; acc += w.z * a2; acc += w.w * a3;
}

// ---------- CSR build ----------
__global__ void k_deg(const int* __restrict__ dst, int* __restrict__ deg) {
    int e = blockIdx.x * 256 + threadIdx.x;
    if (e < EE) atomicAdd(&deg[dst[e]], 1);
}

__global__ void k_scan(const int* __restrict__ deg, int* __restrict__ offsets,
                       float* __restrict__ scal) {
    __shared__ int part[1024];
    __shared__ float fred[1024];
    const int CH = 20;
    int tid = threadIdx.x;
    int base = tid * CH;
    int loc[CH];
    int s = 0; float fs = 0.f;
    for (int c = 0; c < CH; ++c) {
        int idx = base + c;
        int v = (idx < NN) ? deg[idx] : 0;
        loc[c] = s; s += v;
        if (idx < NN) fs += logf((float)v + 1.0f);
    }
    part[tid] = s; fred[tid] = fs; __syncthreads();
    for (int off = 1; off < 1024; off <<= 1) {
        int v = (tid >= off) ? part[tid - off] : 0;
        __syncthreads();
        part[tid] += v;
        __syncthreads();
    }
    int pre = (tid > 0) ? part[tid - 1] : 0;
    for (int c = 0; c < CH; ++c) {
        int idx = base + c;
        if (idx < NN) offsets[idx] = pre + loc[c];
    }
    if (tid == 0) offsets[NN] = part[1023];
    for (int off = 512; off > 0; off >>= 1) {
        if (tid < off) fred[tid] += fred[tid + off];
        __syncthreads();
    }
    if (tid == 0) scal[0] = fred[0] / (float)NN;
}

__global__ void k_fill(const int* __restrict__ src, const int* __restrict__ dst,
                       const int* __restrict__ offsets, int* __restrict__ cursor,
                       int* __restrict__ csr_src) {
    int e = blockIdx.x * 256 + threadIdx.x;
    if (e < EE) {
        int d = dst[e];
        int pos = offsets[d] + atomicAdd(&cursor[d], 1);
        csr_src[pos] = src[e];
    }
}

// ---------- degree binning: histogram -> padded starts -> scatter ----------
__global__ void k_hist(const int* __restrict__ deg, int* __restrict__ hist) {
    int i = blockIdx.x * 256 + threadIdx.x;
    if (i < NN) atomicAdd(&hist[min(deg[i], NBINS - 1)], 1);
}

__global__ void k_binstart(const int* __restrict__ hist, int* __restrict__ padStart) {
    if (threadIdx.x == 0) {
        int acc = 0;
        for (int b = 0; b < NBINS; ++b) {
            padStart[b] = acc;
            acc += (hist[b] + 7) & ~7;
        }
        padStart[NBINS] = acc;
    }
}

__global__ void k_scatter(const int* __restrict__ deg, const int* __restrict__ padStart,
                          int* __restrict__ binCur, int* __restrict__ nodeList,
                          int* __restrict__ slotBin) {
    int i = blockIdx.x * 256 + threadIdx.x;
    if (i < NN) {
        int bin = min(deg[i], NBINS - 1);
        int pos = padStart[bin] + atomicAdd(&binCur[bin], 1);
        nodeList[pos] = i;
        slotBin[pos] = bin;
    }
}

// ---------- build combined per-degree post weights W' = Wi + amp*Wa + ia*Wt ----------
// Wp1: [bin][65 quads][64][4] (segs: x 13q | 4 agg segs 13q each, f padded 50->52)
// Wp0: [bin][20 quads][64][4] (segs: x 4q | 4 agg segs 4q each, F=16)
__global__ void k_wprime(const float* __restrict__ postW0, const float* __restrict__ postW1,
                         const float* __restrict__ scal,
                         float* __restrict__ Wp0, float* __restrict__ Wp1) {
    int bin = blockIdx.y;
    float degf = fmaxf((float)bin, 1.f);
    float amp = logf(degf + 1.f) / scal[0];
    float ia = 1.f / amp;
    int x = blockIdx.x, t = threadIdx.x;
    int k = t >> 2, j = t & 3;
    if (x < 65) {
        int sq = x;
        int seg = sq / 13, q = sq % 13, f = q * 4 + j;
        float v = 0.f;
        if (f < 50 && k < 50) {
            if (seg == 0) v = postW1[k * 650 + f];
            else {
                int s = seg - 1;
                v = postW1[k * 650 + (1 + s) * 50 + f]
                  + amp * postW1[k * 650 + (5 + s) * 50 + f]
                  + ia * postW1[k * 650 + (9 + s) * 50 + f];
            }
        }
        Wp1[((size_t)bin * 65 + sq) * 256 + t] = v;
    } else {
        int sq = x - 65;  // 0..19
        int seg, f;
        if (sq < 4) { seg = 0; f = sq * 4 + j; }
        else { seg = 1 + (sq - 4) / 4; f = ((sq - 4) % 4) * 4 + j; }
        float v = 0.f;
        if (k < 50) {
            if (seg == 0) v = postW0[k * 208 + f];
            else {
                int s = seg - 1;
                v = postW0[k * 208 + (1 + s) * 16 + f]
                  + amp * postW0[k * 208 + (5 + s) * 16 + f]
                  + ia * postW0[k * 208 + (9 + s) * 16 + f];
            }
        }
        Wp0[((size_t)bin * 20 + sq) * 256 + t] = v;
    }
}

// ---------- pack preW transposed + lin transposed ----------
__global__ void k_pack(const float* __restrict__ preW0, const float* __restrict__ preW1,
                       const float* __restrict__ linW0, const float* __restrict__ linW1,
                       float* __restrict__ preWt0, float* __restrict__ preWt1,
                       float* __restrict__ Lt0, float* __restrict__ Lt1) {
    int idx = blockIdx.x * 256 + threadIdx.x;
    int job = blockIdx.y;
    int q = idx >> 8, k = (idx >> 2) & 63, j = idx & 3;
    switch (job) {
    case 0:
        if (idx < 32 * 80) { int c = idx / 80, r = idx % 80; preWt0[idx] = preW0[r * 32 + c]; }
        break;
    case 1:
        if (idx < 100 * 256) { int c = idx / 256, r = idx % 256; preWt1[idx] = (r < 250) ? preW1[r * 100 + c] : 0.f; }
        break;
    case 2:
        if (idx < 13 * 256) { int f = q * 4 + j; Lt0[idx] = (f < 50 && k < HID) ? linW0[k * 50 + f] : 0.f; }
        break;
    case 3:
        if (idx < 13 * 256) { int f = q * 4 + j; Lt1[idx] = (f < 50 && k < HID) ? linW1[k * 50 + f] : 0.f; }
        break;
    }
}

// ---------- C = x@WL^T + b, P = x@WR^T; optional fused BN+ReLU on input load ----------
template <int F, int TF, int TFP, bool BN>
__global__ __launch_bounds__(256, 4) void k_gemm_CP(
    const float* __restrict__ x, const float* __restrict__ preWt,
    const float* __restrict__ b,
    const float* __restrict__ bnacc, const float* __restrict__ gam,
    const float* __restrict__ bet,
    float* __restrict__ C, float* __restrict__ P) {
    const int NODES = 16;
    __shared__ float xs[NODES * F];
    int tid = threadIdx.x;
    int base = blockIdx.x * NODES;
    for (int idx = tid; idx < NODES * F; idx += 256) {
        float v = x[(size_t)base * F + idx];
        if (BN) {
            int c = idx % F;
            float mu = bnacc[c] * (1.f / NN);
            float var = bnacc[64 + c] * (1.f / NN) - mu * mu;
            v = fmaxf(gam[c] * (v - mu) * rsqrtf(var + 1e-5f) + bet[c], 0.f);
        }
        xs[idx] = v;
    }
    __syncthreads();
    if (tid < TF) {
        float accC[NODES], accP[NODES];
#pragma unroll
        for (int n = 0; n < NODES; ++n) { accC[n] = 0.f; accP[n] = 0.f; }
        for (int f = 0; f < F; ++f) {
            float wl = preWt[f * TFP + tid];
            float wr = preWt[(F + f) * TFP + tid];
#pragma unroll
            for (int n = 0; n < NODES; ++n) {
                float xv = xs[n * F + f];
                accC[n] += xv * wl;
                accP[n] += xv * wr;
            }
        }
        float bb = b[tid];
        for (int n = 0; n < NODES; ++n) {
            C[((size_t)(base + n)) * TFP + tid] = accC[n] + bb;
            P[((size_t)(base + n)) * TFP + tid] = accP[n];
        }
    } else if (tid < TFP) {
        for (int n = 0; n < NODES; ++n) {
            C[((size_t)(base + n)) * TFP + tid] = 0.f;
            P[((size_t)(base + n)) * TFP + tid] = 0.f;
        }
    }
}

// ---------- fused conv: degree-binned nodes, combined W', gather + post + lin + BN ----------
// 8 nodes/block (same degree), 4 waves; wave w owns nodes {2w, 2w+1}.
template <int F, int TFPG, int TFPL, int EP, int SQ, int SQX, bool AF4, bool BNIN>
__global__ __launch_bounds__(256, 4) void k_conv(
    const float* __restrict__ xin, const float* __restrict__ C, const float* __restrict__ P,
    const int* __restrict__ offsets, const int* __restrict__ csr,
    const int* __restrict__ nodeList, const int* __restrict__ slotBin,
    const float* __restrict__ Wp,
    const float* __restrict__ postb, const float* __restrict__ Lt,
    const float* __restrict__ linb,
    const float* __restrict__ bn_in, const float* __restrict__ g_in,
    const float* __restrict__ b_in,
    float* __restrict__ hout, float* __restrict__ bn_out) {
    const int GP = TFPG / 4;
    const int GL = TFPL / 4;
    const int WQ = SQX + 4 * SQ;
    __shared__ __align__(16) float sAgg[8][4][TFPL];
    __shared__ __align__(16) float sX[8][SQX * 4];
    __shared__ __align__(16) float sY[8][52];
    __shared__ float sBN[4][2][64];
    int t = threadIdx.x, w = t >> 6, lane = t & 63;
    int sbase = blockIdx.x * 8;
    int nodeId[2];

    for (int nn = 0; nn < 2; ++nn) {
        int nd = 2 * w + nn;
        int i = nodeList[sbase + nd];
        nodeId[nn] = i;
        if (i < 0) continue;  // wave-uniform
        int beg = offsets[i], end = offsets[i + 1];
        int d = end - beg;
        int g = (EP == 1) ? lane : (lane % GL);
        int e = (EP == 1) ? 0 : (lane / GL);
        bool act = (EP == 1) ? (lane < GL) : (e < EP);
        f4 S = {0.f, 0.f, 0.f, 0.f}, S2 = {0.f, 0.f, 0.f, 0.f};
        f4 MN = {FLT_MAX, FLT_MAX, FLT_MAX, FLT_MAX};
        f4 MX = {-FLT_MAX, -FLT_MAX, -FLT_MAX, -FLT_MAX};
        const f4* __restrict__ Pv = (const f4*)P;
        if (act) {
            if (EP == 1) {
                int j = beg;
                for (; j + 4 <= end; j += 4) {
                    int s0 = csr[j], s1 = csr[j + 1], s2 = csr[j + 2], s3 = csr[j + 3];
                    f4 a = Pv[(size_t)s0 * GP + g];
                    f4 b = Pv[(size_t)s1 * GP + g];
                    f4 c = Pv[(size_t)s2 * GP + g];
                    f4 dd = Pv[(size_t)s3 * GP + g];
                    S += a; S2 += a * a; MN = f4_min(MN, a); MX = f4_max(MX, a);
                    S += b; S2 += b * b; MN = f4_min(MN, b); MX = f4_max(MX, b);
                    S += c; S2 += c * c; MN = f4_min(MN, c); MX = f4_max(MX, c);
                    S += dd; S2 += dd * dd; MN = f4_min(MN, dd); MX = f4_max(MX, dd);
                }
                for (; j < end; ++j) {
                    int s0 = csr[j];
                    f4 a = Pv[(size_t)s0 * GP + g];
                    S += a; S2 += a * a; MN = f4_min(MN, a); MX = f4_max(MX, a);
                }
            } else {
                int j = beg + e;
                for (; j + EP < end; j += 2 * EP) {
                    int s0 = csr[j], s1 = csr[j + EP];
                    f4 a = Pv[(size_t)s0 * GP + g];
                    f4 b = Pv[(size_t)s1 * GP + g];
                    S += a; S2 += a * a; MN = f4_min(MN, a); MX = f4_max(MX, a);
                    S += b; S2 += b * b; MN = f4_min(MN, b); MX = f4_max(MX, b);
                }
                if (j < end) {
                    int s0 = csr[j];
                    f4 a = Pv[(size_t)s0 * GP + g];
                    S += a; S2 += a * a; MN = f4_min(MN, a); MX = f4_max(MX, a);
                }
            }
        }
        if (EP == 3) {
            int g0 = lane % GL;
            S.x = sh3sum(S.x, g0, GL); S.y = sh3sum(S.y, g0, GL);
            S.z = sh3sum(S.z, g0, GL); S.w = sh3sum(S.w, g0, GL);
            S2.x = sh3sum(S2.x, g0, GL); S2.y = sh3sum(S2.y, g0, GL);
            S2.z = sh3sum(S2.z, g0, GL); S2.w = sh3sum(S2.w, g0, GL);
            MN.x = sh3min(MN.x, g0, GL); MN.y = sh3min(MN.y, g0, GL);
            MN.z = sh3min(MN.z, g0, GL); MN.w = sh3min(MN.w, g0, GL);
            MX.x = sh3max(MX.x, g0, GL); MX.y = sh3max(MX.y, g0, GL);
            MX.z = sh3max(MX.z, g0, GL); MX.w = sh3max(MX.w, g0, GL);
        }
        if (lane < GL) {
            f4 Cv = ((const f4*)C)[(size_t)i * GP + lane];
            float degf = (float)d;
            float rdegc = 1.0f / fmaxf(degf, 1.0f);
            f4 mean, sq, var, stdv, mnv, mxv;
            mean.x = (degf * Cv.x + S.x) * rdegc; mean.y = (degf * Cv.y + S.y) * rdegc;
            mean.z = (degf * Cv.z + S.z) * rdegc; mean.w = (degf * Cv.w + S.w) * rdegc;
            sq.x = degf * Cv.x * Cv.x + 2.f * Cv.x * S.x + S2.x;
            sq.y = degf * Cv.y * Cv.y + 2.f * Cv.y * S.y + S2.y;
            sq.z = degf * Cv.z * Cv.z + 2.f * Cv.z * S.z + S2.z;
            sq.w = degf * Cv.w * Cv.w + 2.f * Cv.w * S.w + S2.w;
            var.x = sq.x * rdegc - mean.x * mean.x; var.y = sq.y * rdegc - mean.y * mean.y;
            var.z = sq.z * rdegc - mean.z * mean.z; var.w = sq.w * rdegc - mean.w * mean.w;
            stdv.x = sqrtf(fmaxf(var.x, 0.f) + 1e-5f); stdv.y = sqrtf(fmaxf(var.y, 0.f) + 1e-5f);
            stdv.z = sqrtf(fmaxf(var.z, 0.f) + 1e-5f); stdv.w = sqrtf(fmaxf(var.w, 0.f) + 1e-5f);
            if (d > 0) {
                mnv.x = Cv.x + MN.x; mnv.y = Cv.y + MN.y; mnv.z = Cv.z + MN.z; mnv.w = Cv.w + MN.w;
                mxv.x = Cv.x + MX.x; mxv.y = Cv.y + MX.y; mxv.z = Cv.z + MX.z; mxv.w = Cv.w + MX.w;
            } else {
                mnv = (f4){0.f, 0.f, 0.f, 0.f}; mxv = mnv;
            }
            ((f4*)&sAgg[nd][0][0])[lane] = mean;
            ((f4*)&sAgg[nd][1][0])[lane] = mnv;
            ((f4*)&sAgg[nd][2][0])[lane] = mxv;
            ((f4*)&sAgg[nd][3][0])[lane] = stdv;
        }
        if (BNIN) {
            if (lane < F) {
                float hv = xin[(size_t)i * F + lane];
                float mu = bn_in[lane] * (1.f / NN);
                float var = bn_in[64 + lane] * (1.f / NN) - mu * mu;
                sX[nd][lane] = fmaxf(g_in[lane] * (hv - mu) * rsqrtf(var + 1e-5f) + b_in[lane], 0.f);
            } else if (lane < SQX * 4) {
                sX[nd][lane] = 0.f;
            }
        } else {
            if (lane < F) sX[nd][lane] = xin[(size_t)i * F + lane];
            else if (lane < SQX * 4) sX[nd][lane] = 0.f;
        }
    }
    int bin = slotBin[sbase];
    const f4* __restrict__ Wv = (const f4*)(Wp + (size_t)bin * WQ * 256);
    __syncthreads();  // lockstep waves for shared W' stream

    // ---- post-GEMM (combined W'), R=2 ----
    int nd0 = 2 * w, nd1 = 2 * w + 1;
    int kk = (lane < HID) ? lane : (HID - 1);
    int tw = kk / FO;
    float ya = 0.f, yb = 0.f;
#pragma unroll
    for (int q = 0; q < SQX; ++q) {
        f4 wv = Wv[q * 64 + lane];
        f4 a0 = *(const f4*)(&sX[nd0][4 * q]);
        f4 a1 = *(const f4*)(&sX[nd1][4 * q]);
        acc4(ya, wv, a0.x, a0.y, a0.z, a0.w);
        acc4(yb, wv, a1.x, a1.y, a1.z, a1.w);
    }
#pragma unroll
    for (int s = 0; s < 4; ++s) {
        const float* __restrict__ A0 = &sAgg[nd0][s][tw * F];
        const float* __restrict__ A1 = &sAgg[nd1][s][tw * F];
#pragma unroll 4
        for (int q = 0; q < SQ; ++q) {
            f4 wv = Wv[(SQX + s * SQ + q) * 64 + lane];
            float a00, a01, a02, a03, a10, a11, a12, a13;
            if constexpr (AF4) {
                f4 v0 = *(const f4*)(A0 + 4 * q);
                f4 v1 = *(const f4*)(A1 + 4 * q);
                a00 = v0.x; a01 = v0.y; a02 = v0.z; a03 = v0.w;
                a10 = v1.x; a11 = v1.y; a12 = v1.z; a13 = v1.w;
            } else {
                f2 p0 = *(const f2*)(A0 + 4 * q);
                f2 p1 = *(const f2*)(A0 + 4 * q + 2);
                f2 q0 = *(const f2*)(A1 + 4 * q);
                f2 q1 = *(const f2*)(A1 + 4 * q + 2);
                a00 = p0.x; a01 = p0.y; a02 = p1.x; a03 = p1.y;
                a10 = q0.x; a11 = q0.y; a12 = q1.x; a13 = q1.y;
            }
            acc4(ya, wv, a00, a01, a02, a03);
            acc4(yb, wv, a10, a11, a12, a13);
        }
    }
    float pb = postb[kk];
    ya += pb; yb += pb;
    if (lane < HID) { sY[nd0][lane] = ya; sY[nd1][lane] = yb; }
    else if (lane < 52) { sY[nd0][lane] = 0.f; sY[nd1][lane] = 0.f; }
    // wave-private sY: no barrier needed

    // ---- lin ----
    const f4* __restrict__ Lv = (const f4*)Lt;
    float lb = linb[kk];
    float oa = lb, ob = lb;
#pragma unroll
    for (int q = 0; q < 13; ++q) {
        f4 lv = Lv[q * 64 + lane];
        f4 s0 = *(const f4*)(&sY[nd0][4 * q]);
        f4 s1 = *(const f4*)(&sY[nd1][4 * q]);
        acc4(oa, lv, s0.x, s0.y, s0.z, s0.w);
        acc4(ob, lv, s1.x, s1.y, s1.z, s1.w);
    }
    if (lane < HID) {
        if (nodeId[0] >= 0) hout[(size_t)nodeId[0] * HID + lane] = oa;
        if (nodeId[1] >= 0) hout[(size_t)nodeId[1] * HID + lane] = ob;
    }

    // ---- BN partial stats (sentinel-guarded) ----
    float sv = 0.f, sv2 = 0.f;
    if (lane < HID) {
        if (nodeId[0] >= 0) { sv += oa; sv2 += oa * oa; }
        if (nodeId[1] >= 0) { sv += ob; sv2 += ob * ob; }
    }
    sBN[w][0][lane] = sv;
    sBN[w][1][lane] = sv2;
    __syncthreads();
    if (t < 64 && lane < HID) {
        float s = sBN[0][0][lane] + sBN[1][0][lane] + sBN[2][0][lane] + sBN[3][0][lane];
        float s2 = sBN[0][1][lane] + sBN[1][1][lane] + sBN[2][1][lane] + sBN[3][1][lane];
        atomicAdd(&bn_out[lane], s);
        atomicAdd(&bn_out[64 + lane], s2);
    }
}

// ---------- fused bounds + BN+ReLU + pooling + head MLP ----------
__global__ void k_head(const float* __restrict__ h, const int* __restrict__ batch,
                       const float* __restrict__ bnacc, const float* __restrict__ gam,
                       const float* __restrict__ bet,
                       const float* __restrict__ W1, const float* __restrict__ b1,
                       const float* __restrict__ W2, const float* __restrict__ b2,
                       const float* __restrict__ W3, const float* __restrict__ b3,
                       float* __restrict__ out) {
    __shared__ float sp[HID], h1[50], h2[25];
    __shared__ int sbound[2];
    int g = blockIdx.x, tid = threadIdx.x;
    if (tid < 2) {
        int target = g + tid;
        int lo = 0, hi = NN;
        while (lo < hi) {
            int mid = (lo + hi) >> 1;
            if (batch[mid] < target) lo = mid + 1; else hi = mid;
        }
        sbound[tid] = lo;
    }
    __syncthreads();
    int beg = sbound[0], end = sbound[1];
    if (tid < HID) {
        float mu = bnacc[tid] * (1.f / NN);
        float var = bnacc[64 + tid] * (1.f / NN) - mu * mu;
        float sc = gam[tid] * rsqrtf(var + 1e-5f);
        float sh = bet[tid] - mu * sc;
        float s0 = 0.f, s1 = 0.f, s2 = 0.f, s3 = 0.f;
        int n = beg;
        for (; n + 4 <= end; n += 4) {
            s0 += fmaxf(fmaf(h[(size_t)n * HID + tid], sc, sh), 0.f);
            s1 += fmaxf(fmaf(h[(size_t)(n + 1) * HID + tid], sc, sh), 0.f);
            s2 += fmaxf(fmaf(h[(size_t)(n + 2) * HID + tid], sc, sh), 0.f);
            s3 += fmaxf(fmaf(h[(size_t)(n + 3) * HID + tid], sc, sh), 0.f);
        }
        for (; n < end; ++n) s0 += fmaxf(fmaf(h[(size_t)n * HID + tid], sc, sh), 0.f);
        sp[tid] = (s0 + s1 + s2 + s3) / fmaxf((float)(end - beg), 1.0f);
    }
    __syncthreads();
    if (tid < 50) {
        float a = b1[tid];
        for (int k = 0; k < HID; ++k) a += W1[tid * HID + k] * sp[k];
        h1[tid] = fmaxf(a, 0.f);
    }
    __syncthreads();
    if (tid < 25) {
        float a = b2[tid];
        for (int k = 0; k < 50; ++k) a += W2[tid * 50 + k] * h1[k];
        h2[tid] = fmaxf(a, 0.f);
    }
    __syncthreads();
    if (tid == 0) {
        float a = b3[0];
        for (int k = 0; k < 25; ++k) a += W3[k] * h2[k];
        out[g] = a;
    }
}

extern "C" void kernel_launch(void* const* d_in, const int* in_sizes, int n_in,
                              void* d_out, int out_size, void* d_ws, size_t ws_size,
                              hipStream_t stream) {
    const float* x      = (const float*)d_in[0];
    const int*   ei     = (const int*)d_in[1];
    const int*   batch  = (const int*)d_in[2];
    const float* preW0  = (const float*)d_in[3];
    const float* preb0  = (const float*)d_in[4];
    const float* postW0 = (const float*)d_in[5];
    const float* postb0 = (const float*)d_in[6];
    const float* linW0  = (const float*)d_in[7];
    const float* linb0  = (const float*)d_in[8];
    const float* gamma0 = (const float*)d_in[9];
    const float* beta0  = (const float*)d_in[10];
    const float* preW1  = (const float*)d_in[11];
    const float* preb1  = (const float*)d_in[12];
    const float* postW1 = (const float*)d_in[13];
    const float* postb1 = (const float*)d_in[14];
    const float* linW1  = (const float*)d_in[15];
    const float* linb1  = (const float*)d_in[16];
    const float* gamma1 = (const float*)d_in[17];
    const float* beta1  = (const float*)d_in[18];
    const float* mW1    = (const float*)d_in[19];
    const float* mb1    = (const float*)d_in[20];
    const float* mW2    = (const float*)d_in[21];
    const float* mb2    = (const float*)d_in[22];
    const float* mW3    = (const float*)d_in[23];
    const float* mb3    = (const float*)d_in[24];
    float* out = (float*)d_out;
    (void)in_sizes; (void)n_in; (void)out_size; (void)ws_size;

    char* ws = (char*)d_ws;
    size_t off = 0;
    auto alloc = [&](size_t bytes) -> void* {
        void* p = ws + off;
        off += (bytes + 255) & ~(size_t)255;
        return p;
    };
    // zero-region (one memset): deg, cursor, bnacc0/1, hist, binCur, slotBin
    int*   deg     = (int*)alloc((size_t)NN * 4);
    int*   cursor  = (int*)alloc((size_t)NN * 4);
    float* bnacc0  = (float*)alloc(128 * 4);
    float* bnacc1  = (float*)alloc(128 * 4);
    int*   hist    = (int*)alloc(NBINS * 4);
    int*   binCur  = (int*)alloc(NBINS * 4);
    int*   slotBin = (int*)alloc((size_t)(NBLK * 8) * 4);
    size_t zero_bytes = off;
    int*   nodeList = (int*)alloc((size_t)(NBLK * 8) * 4);
    int*   padStart = (int*)alloc((NBINS + 1) * 4);
    int*   offsets = (int*)alloc((size_t)(NN + 1) * 4);
    int*   csr_src = (int*)alloc((size_t)EE * 4);
    float* scal    = (float*)alloc(64);
    float* preWt0  = (float*)alloc((size_t)32 * 80 * 4);
    float* preWt1  = (float*)alloc((size_t)100 * 256 * 4);
    float* Lt0     = (float*)alloc((size_t)13 * 256 * 4);
    float* Lt1     = (float*)alloc((size_t)13 * 256 * 4);
    float* Wp0     = (float*)alloc((size_t)NBINS * 20 * 256 * 4);
    float* Wp1     = (float*)alloc((size_t)NBINS * 65 * 256 * 4);
    float* Cbuf    = (float*)alloc((size_t)NN * 256 * 4);
    float* Pbuf    = (float*)alloc((size_t)NN * 256 * 4);
    float* h1buf   = (float*)alloc((size_t)NN * HID * 4);
    float* h2buf   = (float*)alloc((size_t)NN * HID * 4);

    const int* src = ei;
    const int* dst = ei + EE;

    hipMemsetAsync(ws, 0, zero_bytes, stream);
    hipMemsetAsync(nodeList, 0xFF, (size_t)(NBLK * 8) * 4, stream);

    k_pack<<<dim3(100, 4), 256, 0, stream>>>(preW0, preW1, linW0, linW1,
                                             preWt0, preWt1, Lt0, Lt1);
    k_deg<<<EE / 256, 256, 0, stream>>>(dst, deg);
    k_scan<<<1, 1024, 0, stream>>>(deg, offsets, scal);
    k_fill<<<EE / 256, 256, 0, stream>>>(src, dst, offsets, cursor, csr_src);
    k_hist<<<(NN + 255) / 256, 256, 0, stream>>>(deg, hist);
    k_binstart<<<1, 64, 0, stream>>>(hist, padStart);
    k_scatter<<<(NN + 255) / 256, 256, 0, stream>>>(deg, padStart, binCur, nodeList, slotBin);
    k_wprime<<<dim3(85, NBINS), 256, 0, stream>>>(postW0, postW1, scal, Wp0, Wp1);

    // ---- conv0 (F=16, TFPG=TFPL=80, EP=3, SQ=4, SQX=4) ----
    k_gemm_CP<INDIM, 80, 80, false><<<NN / 16, 256, 0, stream>>>(
        x, preWt0, preb0, nullptr, nullptr, nullptr, Cbuf, Pbuf);
    k_conv<INDIM, 80, 80, 3, 4, 4, true, false><<<NBLK, 256, 0, stream>>>(
        x, Cbuf, Pbuf, offsets, csr_src, nodeList, slotBin, Wp0, postb0, Lt0, linb0,
        nullptr, nullptr, nullptr, h1buf, bnacc0);

    // ---- conv1 (F=50, TFPG=256, TFPL=252, EP=1, SQ=13, SQX=13); BN0 fused ----
    k_gemm_CP<HID, 250, 256, true><<<NN / 16, 256, 0, stream>>>(
        h1buf, preWt1, preb1, bnacc0, gamma0, beta0, Cbuf, Pbuf);
    k_conv<HID, 256, 252, 1, 13, 13, false, true><<<NBLK, 256, 0, stream>>>(
        h1buf, Cbuf, Pbuf, offsets, csr_src, nodeList, slotBin, Wp1, postb1, Lt1, linb1,
        bnacc0, gamma0, beta0, h2buf, bnacc1);

    // ---- BN1+ReLU fused into pooling + head ----
    k_head<<<NGROUPS, 64, 0, stream>>>(h2buf, batch, bnacc1, gamma1, beta1,
                                       mW1, mb1, mW2, mb2, mW3, mb3, out);
}

// Round 10
// 366.320 us; speedup vs baseline: 1.1708x; 1.1708x over previous
//
#include <hip/hip_runtime.h>
#include <math.h>
#include <float.h>

#define NN 20000
#define EE 320000
#define INDIM 16
#define HID 50
#define TW 5
#define FO 10
#define NGROUPS 64
#define NBINS 64
#define NBLK 2556   // (NN + NBINS*7)/8 rounded up

typedef float f4 __attribute__((ext_vector_type(4)));
typedef float f2 __attribute__((ext_vector_type(2)));
typedef _Float16 h4 __attribute__((ext_vector_type(4)));

__device__ inline f4 f4_min(f4 a, f4 b) {
    f4 r; r.x = fminf(a.x, b.x); r.y = fminf(a.y, b.y);
    r.z = fminf(a.z, b.z); r.w = fminf(a.w, b.w); return r;
}
__device__ inline f4 f4_max(f4 a, f4 b) {
    f4 r; r.x = fmaxf(a.x, b.x); r.y = fmaxf(a.y, b.y);
    r.z = fmaxf(a.z, b.z); r.w = fmaxf(a.w, b.w); return r;
}
__device__ inline f4 h2f(h4 h) {
    f4 r; r.x = (float)h.x; r.y = (float)h.y; r.z = (float)h.z; r.w = (float)h.w; return r;
}
__device__ inline float sh3sum(float v, int g0, int G_) {
    return v + __shfl(v, g0 + G_, 64) + __shfl(v, g0 + 2 * G_, 64);
}
__device__ inline float sh3min(float v, int g0, int G_) {
    return fminf(fminf(v, __shfl(v, g0 + G_, 64)), __shfl(v, g0 + 2 * G_, 64));
}
__device__ inline float sh3max(float v, int g0, int G_) {
    return fmaxf(fmaxf(v, __shfl(v, g0 + G_, 64)), __shfl(v, g0 + 2 * G_, 64));
}
__device__ inline void acc4(float& acc, f4 w, float a0, float a1, float a2, float a3) {
    acc += w.x * a0; acc += w.y * a1; acc += w.z * a2; acc += w.w * a3;
}

// ---------- CSR build ----------
__global__ void k_deg(const int* __restrict__ dst, int* __restrict__ deg) {
    int e = blockIdx.x * 256 + threadIdx.x;
    if (e < EE) atomicAdd(&deg[dst[e]], 1);
}

// scan of degrees -> offsets, avg_log, degree histogram -> padded bin starts
__global__ void k_scan(const int* __restrict__ deg, int* __restrict__ offsets,
                       float* __restrict__ scal, int* __restrict__ padStart) {
    __shared__ int part[1024];
    __shared__ float fred[1024];
    __shared__ int lhist[NBINS];
    const int CH = 20;
    int tid = threadIdx.x;
    if (tid < NBINS) lhist[tid] = 0;
    __syncthreads();
    int base = tid * CH;
    int loc[CH];
    int s = 0; float fs = 0.f;
    for (int c = 0; c < CH; ++c) {
        int idx = base + c;
        int v = (idx < NN) ? deg[idx] : 0;
        loc[c] = s; s += v;
        if (idx < NN) {
            fs += logf((float)v + 1.0f);
            atomicAdd(&lhist[min(v, NBINS - 1)], 1);
        }
    }
    part[tid] = s; fred[tid] = fs; __syncthreads();
    for (int off = 1; off < 1024; off <<= 1) {
        int v = (tid >= off) ? part[tid - off] : 0;
        __syncthreads();
        part[tid] += v;
        __syncthreads();
    }
    int pre = (tid > 0) ? part[tid - 1] : 0;
    for (int c = 0; c < CH; ++c) {
        int idx = base + c;
        if (idx < NN) offsets[idx] = pre + loc[c];
    }
    if (tid == 0) offsets[NN] = part[1023];
    for (int off = 512; off > 0; off >>= 1) {
        if (tid < off) fred[tid] += fred[tid + off];
        __syncthreads();
    }
    if (tid == 0) {
        scal[0] = fred[0] / (float)NN;
        int acc = 0;
        for (int b = 0; b < NBINS; ++b) {
            padStart[b] = acc;
            acc += (lhist[b] + 7) & ~7;
        }
        padStart[NBINS] = acc;
    }
}

__global__ void k_fill(const int* __restrict__ src, const int* __restrict__ dst,
                       const int* __restrict__ offsets, int* __restrict__ cursor,
                       int* __restrict__ csr_src) {
    int e = blockIdx.x * 256 + threadIdx.x;
    if (e < EE) {
        int d = dst[e];
        int pos = offsets[d] + atomicAdd(&cursor[d], 1);
        csr_src[pos] = src[e];
    }
}

__global__ void k_scatter(const int* __restrict__ deg, const int* __restrict__ padStart,
                          int* __restrict__ binCur, int* __restrict__ nodeList,
                          int* __restrict__ slotBin) {
    int i = blockIdx.x * 256 + threadIdx.x;
    if (i < NN) {
        int bin = min(deg[i], NBINS - 1);
        int pos = padStart[bin] + atomicAdd(&binCur[bin], 1);
        nodeList[pos] = i;
        slotBin[pos] = bin;
    }
}

// ---------- build combined per-degree post weights W' = Wi + amp*Wa + ia*Wt ----------
__global__ void k_wprime(const float* __restrict__ postW0, const float* __restrict__ postW1,
                         const float* __restrict__ scal,
                         float* __restrict__ Wp0, float* __restrict__ Wp1) {
    int bin = blockIdx.y;
    float degf = fmaxf((float)bin, 1.f);
    float amp = logf(degf + 1.f) / scal[0];
    float ia = 1.f / amp;
    int x = blockIdx.x, t = threadIdx.x;
    int k = t >> 2, j = t & 3;
    if (x < 65) {
        int sq = x;
        int seg = sq / 13, q = sq % 13, f = q * 4 + j;
        float v = 0.f;
        if (f < 50 && k < 50) {
            if (seg == 0) v = postW1[k * 650 + f];
            else {
                int s = seg - 1;
                v = postW1[k * 650 + (1 + s) * 50 + f]
                  + amp * postW1[k * 650 + (5 + s) * 50 + f]
                  + ia * postW1[k * 650 + (9 + s) * 50 + f];
            }
        }
        Wp1[((size_t)bin * 65 + sq) * 256 + t] = v;
    } else {
        int sq = x - 65;  // 0..19
        int seg, f;
        if (sq < 4) { seg = 0; f = sq * 4 + j; }
        else { seg = 1 + (sq - 4) / 4; f = ((sq - 4) % 4) * 4 + j; }
        float v = 0.f;
        if (k < 50) {
            if (seg == 0) v = postW0[k * 208 + f];
            else {
                int s = seg - 1;
                v = postW0[k * 208 + (1 + s) * 16 + f]
                  + amp * postW0[k * 208 + (5 + s) * 16 + f]
                  + ia * postW0[k * 208 + (9 + s) * 16 + f];
            }
        }
        Wp0[((size_t)bin * 20 + sq) * 256 + t] = v;
    }
}

// ---------- pack preW transposed + lin transposed ----------
__global__ void k_pack(const float* __restrict__ preW0, const float* __restrict__ preW1,
                       const float* __restrict__ linW0, const float* __restrict__ linW1,
                       float* __restrict__ preWt0, float* __restrict__ preWt1,
                       float* __restrict__ Lt0, float* __restrict__ Lt1) {
    int idx = blockIdx.x * 256 + threadIdx.x;
    int job = blockIdx.y;
    int q = idx >> 8, k = (idx >> 2) & 63, j = idx & 3;
    switch (job) {
    case 0:
        if (idx < 32 * 80) { int c = idx / 80, r = idx % 80; preWt0[idx] = preW0[r * 32 + c]; }
        break;
    case 1:
        if (idx < 100 * 256) { int c = idx / 256, r = idx % 256; preWt1[idx] = (r < 250) ? preW1[r * 100 + c] : 0.f; }
        break;
    case 2:
        if (idx < 13 * 256) { int f = q * 4 + j; Lt0[idx] = (f < 50 && k < HID) ? linW0[k * 50 + f] : 0.f; }
        break;
    case 3:
        if (idx < 13 * 256) { int f = q * 4 + j; Lt1[idx] = (f < 50 && k < HID) ? linW1[k * 50 + f] : 0.f; }
        break;
    }
}

// ---------- C = x@WL^T + b (fp32), P = x@WR^T (fp16); optional fused BN+ReLU ----------
template <int F, int TF, int TFP, bool BN>
__global__ __launch_bounds__(256, 4) void k_gemm_CP(
    const float* __restrict__ x, const float* __restrict__ preWt,
    const float* __restrict__ b,
    const float* __restrict__ bnacc, const float* __restrict__ gam,
    const float* __restrict__ bet,
    float* __restrict__ C, _Float16* __restrict__ P) {
    const int NODES = 16;
    __shared__ float xs[NODES * F];
    int tid = threadIdx.x;
    int base = blockIdx.x * NODES;
    for (int idx = tid; idx < NODES * F; idx += 256) {
        float v = x[(size_t)base * F + idx];
        if (BN) {
            int c = idx % F;
            float mu = bnacc[c] * (1.f / NN);
            float var = bnacc[64 + c] * (1.f / NN) - mu * mu;
            v = fmaxf(gam[c] * (v - mu) * rsqrtf(var + 1e-5f) + bet[c], 0.f);
        }
        xs[idx] = v;
    }
    __syncthreads();
    if (tid < TF) {
        float accC[NODES], accP[NODES];
#pragma unroll
        for (int n = 0; n < NODES; ++n) { accC[n] = 0.f; accP[n] = 0.f; }
        for (int f = 0; f < F; ++f) {
            float wl = preWt[f * TFP + tid];
            float wr = preWt[(F + f) * TFP + tid];
#pragma unroll
            for (int n = 0; n < NODES; ++n) {
                float xv = xs[n * F + f];
                accC[n] += xv * wl;
                accP[n] += xv * wr;
            }
        }
        float bb = b[tid];
        for (int n = 0; n < NODES; ++n) {
            C[((size_t)(base + n)) * TFP + tid] = accC[n] + bb;
            P[((size_t)(base + n)) * TFP + tid] = (_Float16)accP[n];
        }
    } else if (tid < TFP) {
        for (int n = 0; n < NODES; ++n) {
            C[((size_t)(base + n)) * TFP + tid] = 0.f;
            P[((size_t)(base + n)) * TFP + tid] = (_Float16)0.f;
        }
    }
}

// ---------- fused conv: degree-binned nodes, combined W', fp16 gather + post + lin + BN ----------
// 8 nodes/block (same degree), 4 waves; wave w owns nodes {2w, 2w+1}.
template <int F, int TFPG, int TFPL, int EP, int SQ, int SQX, bool AF4, bool BNIN>
__global__ __launch_bounds__(256, 4) void k_conv(
    const float* __restrict__ xin, const float* __restrict__ C, const _Float16* __restrict__ P,
    const int* __restrict__ offsets, const int* __restrict__ csr,
    const int* __restrict__ nodeList, const int* __restrict__ slotBin,
    const float* __restrict__ Wp,
    const float* __restrict__ postb, const float* __restrict__ Lt,
    const float* __restrict__ linb,
    const float* __restrict__ bn_in, const float* __restrict__ g_in,
    const float* __restrict__ b_in,
    float* __restrict__ hout, float* __restrict__ bn_out) {
    const int GP = TFPG / 4;
    const int GL = TFPL / 4;
    const int WQ = SQX + 4 * SQ;
    __shared__ __align__(16) float sAgg[8][4][TFPL];
    __shared__ __align__(16) float sX[8][SQX * 4];
    __shared__ __align__(16) float sY[8][52];
    __shared__ float sBN[4][2][64];
    int t = threadIdx.x, w = t >> 6, lane = t & 63;
    int sbase = blockIdx.x * 8;
    int nodeId[2];

    for (int nn = 0; nn < 2; ++nn) {
        int nd = 2 * w + nn;
        int i = nodeList[sbase + nd];
        nodeId[nn] = i;
        if (i < 0) continue;  // wave-uniform
        int beg = offsets[i], end = offsets[i + 1];
        int d = end - beg;
        int g = (EP == 1) ? lane : (lane % GL);
        int e = (EP == 1) ? 0 : (lane / GL);
        bool act = (EP == 1) ? (lane < GL) : (e < EP);
        f4 S = {0.f, 0.f, 0.f, 0.f}, S2 = {0.f, 0.f, 0.f, 0.f};
        f4 MN = {FLT_MAX, FLT_MAX, FLT_MAX, FLT_MAX};
        f4 MX = {-FLT_MAX, -FLT_MAX, -FLT_MAX, -FLT_MAX};
        const h4* __restrict__ Pv = (const h4*)P;
        if (act) {
            if (EP == 1) {
                int j = beg;
                for (; j + 4 <= end; j += 4) {
                    int s0 = csr[j], s1 = csr[j + 1], s2 = csr[j + 2], s3 = csr[j + 3];
                    f4 a = h2f(Pv[(size_t)s0 * GP + g]);
                    f4 b = h2f(Pv[(size_t)s1 * GP + g]);
                    f4 c = h2f(Pv[(size_t)s2 * GP + g]);
                    f4 dd = h2f(Pv[(size_t)s3 * GP + g]);
                    S += a; S2 += a * a; MN = f4_min(MN, a); MX = f4_max(MX, a);
                    S += b; S2 += b * b; MN = f4_min(MN, b); MX = f4_max(MX, b);
                    S += c; S2 += c * c; MN = f4_min(MN, c); MX = f4_max(MX, c);
                    S += dd; S2 += dd * dd; MN = f4_min(MN, dd); MX = f4_max(MX, dd);
                }
                for (; j < end; ++j) {
                    int s0 = csr[j];
                    f4 a = h2f(Pv[(size_t)s0 * GP + g]);
                    S += a; S2 += a * a; MN = f4_min(MN, a); MX = f4_max(MX, a);
                }
            } else {
                int j = beg + e;
                for (; j + EP < end; j += 2 * EP) {
                    int s0 = csr[j], s1 = csr[j + EP];
                    f4 a = h2f(Pv[(size_t)s0 * GP + g]);
                    f4 b = h2f(Pv[(size_t)s1 * GP + g]);
                    S += a; S2 += a * a; MN = f4_min(MN, a); MX = f4_max(MX, a);
                    S += b; S2 += b * b; MN = f4_min(MN, b); MX = f4_max(MX, b);
                }
                if (j < end) {
                    int s0 = csr[j];
                    f4 a = h2f(Pv[(size_t)s0 * GP + g]);
                    S += a; S2 += a * a; MN = f4_min(MN, a); MX = f4_max(MX, a);
                }
            }
        }
        if (EP == 3) {
            int g0 = lane % GL;
            S.x = sh3sum(S.x, g0, GL); S.y = sh3sum(S.y, g0, GL);
            S.z = sh3sum(S.z, g0, GL); S.w = sh3sum(S.w, g0, GL);
            S2.x = sh3sum(S2.x, g0, GL); S2.y = sh3sum(S2.y, g0, GL);
            S2.z = sh3sum(S2.z, g0, GL); S2.w = sh3sum(S2.w, g0, GL);
            MN.x = sh3min(MN.x, g0, GL); MN.y = sh3min(MN.y, g0, GL);
            MN.z = sh3min(MN.z, g0, GL); MN.w = sh3min(MN.w, g0, GL);
            MX.x = sh3max(MX.x, g0, GL); MX.y = sh3max(MX.y, g0, GL);
            MX.z = sh3max(MX.z, g0, GL); MX.w = sh3max(MX.w, g0, GL);
        }
        if (lane < GL) {
            f4 Cv = ((const f4*)C)[(size_t)i * GP + lane];
            float degf = (float)d;
            float rdegc = 1.0f / fmaxf(degf, 1.0f);
            f4 mean, sq, var, stdv, mnv, mxv;
            mean.x = (degf * Cv.x + S.x) * rdegc; mean.y = (degf * Cv.y + S.y) * rdegc;
            mean.z = (degf * Cv.z + S.z) * rdegc; mean.w = (degf * Cv.w + S.w) * rdegc;
            sq.x = degf * Cv.x * Cv.x + 2.f * Cv.x * S.x + S2.x;
            sq.y = degf * Cv.y * Cv.y + 2.f * Cv.y * S.y + S2.y;
            sq.z = degf * Cv.z * Cv.z + 2.f * Cv.z * S.z + S2.z;
            sq.w = degf * Cv.w * Cv.w + 2.f * Cv.w * S.w + S2.w;
            var.x = sq.x * rdegc - mean.x * mean.x; var.y = sq.y * rdegc - mean.y * mean.y;
            var.z = sq.z * rdegc - mean.z * mean.z; var.w = sq.w * rdegc - mean.w * mean.w;
            stdv.x = sqrtf(fmaxf(var.x, 0.f) + 1e-5f); stdv.y = sqrtf(fmaxf(var.y, 0.f) + 1e-5f);
            stdv.z = sqrtf(fmaxf(var.z, 0.f) + 1e-5f); stdv.w = sqrtf(fmaxf(var.w, 0.f) + 1e-5f);
            if (d > 0) {
                mnv.x = Cv.x + MN.x; mnv.y = Cv.y + MN.y; mnv.z = Cv.z + MN.z; mnv.w = Cv.w + MN.w;
                mxv.x = Cv.x + MX.x; mxv.y = Cv.y + MX.y; mxv.z = Cv.z + MX.z; mxv.w = Cv.w + MX.w;
            } else {
                mnv = (f4){0.f, 0.f, 0.f, 0.f}; mxv = mnv;
            }
            ((f4*)&sAgg[nd][0][0])[lane] = mean;
            ((f4*)&sAgg[nd][1][0])[lane] = mnv;
            ((f4*)&sAgg[nd][2][0])[lane] = mxv;
            ((f4*)&sAgg[nd][3][0])[lane] = stdv;
        }
        if (BNIN) {
            if (lane < F) {
                float hv = xin[(size_t)i * F + lane];
                float mu = bn_in[lane] * (1.f / NN);
                float var = bn_in[64 + lane] * (1.f / NN) - mu * mu;
                sX[nd][lane] = fmaxf(g_in[lane] * (hv - mu) * rsqrtf(var + 1e-5f) + b_in[lane], 0.f);
            } else if (lane < SQX * 4) {
                sX[nd][lane] = 0.f;
            }
        } else {
            if (lane < F) sX[nd][lane] = xin[(size_t)i * F + lane];
            else if (lane < SQX * 4) sX[nd][lane] = 0.f;
        }
    }
    int bin = slotBin[sbase];
    const f4* __restrict__ Wv = (const f4*)(Wp + (size_t)bin * WQ * 256);
    __syncthreads();  // lockstep waves for shared W' stream

    // ---- post-GEMM (combined W'), R=2 ----
    int nd0 = 2 * w, nd1 = 2 * w + 1;
    int kk = (lane < HID) ? lane : (HID - 1);
    int tw = kk / FO;
    float ya = 0.f, yb = 0.f;
#pragma unroll
    for (int q = 0; q < SQX; ++q) {
        f4 wv = Wv[q * 64 + lane];
        f4 a0 = *(const f4*)(&sX[nd0][4 * q]);
        f4 a1 = *(const f4*)(&sX[nd1][4 * q]);
        acc4(ya, wv, a0.x, a0.y, a0.z, a0.w);
        acc4(yb, wv, a1.x, a1.y, a1.z, a1.w);
    }
#pragma unroll
    for (int s = 0; s < 4; ++s) {
        const float* __restrict__ A0 = &sAgg[nd0][s][tw * F];
        const float* __restrict__ A1 = &sAgg[nd1][s][tw * F];
#pragma unroll 4
        for (int q = 0; q < SQ; ++q) {
            f4 wv = Wv[(SQX + s * SQ + q) * 64 + lane];
            float a00, a01, a02, a03, a10, a11, a12, a13;
            if constexpr (AF4) {
                f4 v0 = *(const f4*)(A0 + 4 * q);
                f4 v1 = *(const f4*)(A1 + 4 * q);
                a00 = v0.x; a01 = v0.y; a02 = v0.z; a03 = v0.w;
                a10 = v1.x; a11 = v1.y; a12 = v1.z; a13 = v1.w;
            } else {
                f2 p0 = *(const f2*)(A0 + 4 * q);
                f2 p1 = *(const f2*)(A0 + 4 * q + 2);
                f2 q0 = *(const f2*)(A1 + 4 * q);
                f2 q1 = *(const f2*)(A1 + 4 * q + 2);
                a00 = p0.x; a01 = p0.y; a02 = p1.x; a03 = p1.y;
                a10 = q0.x; a11 = q0.y; a12 = q1.x; a13 = q1.y;
            }
            acc4(ya, wv, a00, a01, a02, a03);
            acc4(yb, wv, a10, a11, a12, a13);
        }
    }
    float pb = postb[kk];
    ya += pb; yb += pb;
    if (lane < HID) { sY[nd0][lane] = ya; sY[nd1][lane] = yb; }
    else if (lane < 52) { sY[nd0][lane] = 0.f; sY[nd1][lane] = 0.f; }
    // wave-private sY: no barrier needed

    // ---- lin ----
    const f4* __restrict__ Lv = (const f4*)Lt;
    float lb = linb[kk];
    float oa = lb, ob = lb;
#pragma unroll
    for (int q = 0; q < 13; ++q) {
        f4 lv = Lv[q * 64 + lane];
        f4 s0 = *(const f4*)(&sY[nd0][4 * q]);
        f4 s1 = *(const f4*)(&sY[nd1][4 * q]);
        acc4(oa, lv, s0.x, s0.y, s0.z, s0.w);
        acc4(ob, lv, s1.x, s1.y, s1.z, s1.w);
    }
    if (lane < HID) {
        if (nodeId[0] >= 0) hout[(size_t)nodeId[0] * HID + lane] = oa;
        if (nodeId[1] >= 0) hout[(size_t)nodeId[1] * HID + lane] = ob;
    }

    // ---- BN partial stats (sentinel-guarded) ----
    float sv = 0.f, sv2 = 0.f;
    if (lane < HID) {
        if (nodeId[0] >= 0) { sv += oa; sv2 += oa * oa; }
        if (nodeId[1] >= 0) { sv += ob; sv2 += ob * ob; }
    }
    sBN[w][0][lane] = sv;
    sBN[w][1][lane] = sv2;
    __syncthreads();
    if (t < 64 && lane < HID) {
        float s = sBN[0][0][lane] + sBN[1][0][lane] + sBN[2][0][lane] + sBN[3][0][lane];
        float s2 = sBN[0][1][lane] + sBN[1][1][lane] + sBN[2][1][lane] + sBN[3][1][lane];
        atomicAdd(&bn_out[lane], s);
        atomicAdd(&bn_out[64 + lane], s2);
    }
}

// ---------- fused bounds + BN+ReLU + pooling + head MLP ----------
__global__ void k_head(const float* __restrict__ h, const int* __restrict__ batch,
                       const float* __restrict__ bnacc, const float* __restrict__ gam,
                       const float* __restrict__ bet,
                       const float* __restrict__ W1, const float* __restrict__ b1,
                       const float* __restrict__ W2, const float* __restrict__ b2,
                       const float* __restrict__ W3, const float* __restrict__ b3,
                       float* __restrict__ out) {
    __shared__ float sp[HID], h1[50], h2[25];
    __shared__ int sbound[2];
    int g = blockIdx.x, tid = threadIdx.x;
    if (tid < 2) {
        int target = g + tid;
        int lo = 0, hi = NN;
        while (lo < hi) {
            int mid = (lo + hi) >> 1;
            if (batch[mid] < target) lo = mid + 1; else hi = mid;
        }
        sbound[tid] = lo;
    }
    __syncthreads();
    int beg = sbound[0], end = sbound[1];
    if (tid < HID) {
        float mu = bnacc[tid] * (1.f / NN);
        float var = bnacc[64 + tid] * (1.f / NN) - mu * mu;
        float sc = gam[tid] * rsqrtf(var + 1e-5f);
        float sh = bet[tid] - mu * sc;
        float s0 = 0.f, s1 = 0.f, s2 = 0.f, s3 = 0.f;
        int n = beg;
        for (; n + 4 <= end; n += 4) {
            s0 += fmaxf(fmaf(h[(size_t)n * HID + tid], sc, sh), 0.f);
            s1 += fmaxf(fmaf(h[(size_t)(n + 1) * HID + tid], sc, sh), 0.f);
            s2 += fmaxf(fmaf(h[(size_t)(n + 2) * HID + tid], sc, sh), 0.f);
            s3 += fmaxf(fmaf(h[(size_t)(n + 3) * HID + tid], sc, sh), 0.f);
        }
        for (; n < end; ++n) s0 += fmaxf(fmaf(h[(size_t)n * HID + tid], sc, sh), 0.f);
        sp[tid] = (s0 + s1 + s2 + s3) / fmaxf((float)(end - beg), 1.0f);
    }
    __syncthreads();
    if (tid < 50) {
        float a = b1[tid];
        for (int k = 0; k < HID; ++k) a += W1[tid * HID + k] * sp[k];
        h1[tid] = fmaxf(a, 0.f);
    }
    __syncthreads();
    if (tid < 25) {
        float a = b2[tid];
        for (int k = 0; k < 50; ++k) a += W2[tid * 50 + k] * h1[k];
        h2[tid] = fmaxf(a, 0.f);
    }
    __syncthreads();
    if (tid == 0) {
        float a = b3[0];
        for (int k = 0; k < 25; ++k) a += W3[k] * h2[k];
        out[g] = a;
    }
}

extern "C" void kernel_launch(void* const* d_in, const int* in_sizes, int n_in,
                              void* d_out, int out_size, void* d_ws, size_t ws_size,
                              hipStream_t stream) {
    const float* x      = (const float*)d_in[0];
    const int*   ei     = (const int*)d_in[1];
    const int*   batch  = (const int*)d_in[2];
    const float* preW0  = (const float*)d_in[3];
    const float* preb0  = (const float*)d_in[4];
    const float* postW0 = (const float*)d_in[5];
    const float* postb0 = (const float*)d_in[6];
    const float* linW0  = (const float*)d_in[7];
    const float* linb0  = (const float*)d_in[8];
    const float* gamma0 = (const float*)d_in[9];
    const float* beta0  = (const float*)d_in[10];
    const float* preW1  = (const float*)d_in[11];
    const float* preb1  = (const float*)d_in[12];
    const float* postW1 = (const float*)d_in[13];
    const float* postb1 = (const float*)d_in[14];
    const float* linW1  = (const float*)d_in[15];
    const float* linb1  = (const float*)d_in[16];
    const float* gamma1 = (const float*)d_in[17];
    const float* beta1  = (const float*)d_in[18];
    const float* mW1    = (const float*)d_in[19];
    const float* mb1    = (const float*)d_in[20];
    const float* mW2    = (const float*)d_in[21];
    const float* mb2    = (const float*)d_in[22];
    const float* mW3    = (const float*)d_in[23];
    const float* mb3    = (const float*)d_in[24];
    float* out = (float*)d_out;
    (void)in_sizes; (void)n_in; (void)out_size; (void)ws_size;

    char* ws = (char*)d_ws;
    size_t off = 0;
    auto alloc = [&](size_t bytes) -> void* {
        void* p = ws + off;
        off += (bytes + 255) & ~(size_t)255;
        return p;
    };
    // zero-region (one memset): deg, cursor, bnacc0/1, binCur, slotBin
    int*   deg     = (int*)alloc((size_t)NN * 4);
    int*   cursor  = (int*)alloc((size_t)NN * 4);
    float* bnacc0  = (float*)alloc(128 * 4);
    float* bnacc1  = (float*)alloc(128 * 4);
    int*   binCur  = (int*)alloc(NBINS * 4);
    int*   slotBin = (int*)alloc((size_t)(NBLK * 8) * 4);
    size_t zero_bytes = off;
    int*   nodeList = (int*)alloc((size_t)(NBLK * 8) * 4);
    int*   padStart = (int*)alloc((NBINS + 1) * 4);
    int*   offsets = (int*)alloc((size_t)(NN + 1) * 4);
    int*   csr_src = (int*)alloc((size_t)EE * 4);
    float* scal    = (float*)alloc(64);
    float* preWt0  = (float*)alloc((size_t)32 * 80 * 4);
    float* preWt1  = (float*)alloc((size_t)100 * 256 * 4);
    float* Lt0     = (float*)alloc((size_t)13 * 256 * 4);
    float* Lt1     = (float*)alloc((size_t)13 * 256 * 4);
    float* Wp0     = (float*)alloc((size_t)NBINS * 20 * 256 * 4);
    float* Wp1     = (float*)alloc((size_t)NBINS * 65 * 256 * 4);
    float* Cbuf    = (float*)alloc((size_t)NN * 256 * 4);
    _Float16* Pbuf = (_Float16*)alloc((size_t)NN * 256 * 2);
    float* h1buf   = (float*)alloc((size_t)NN * HID * 4);
    float* h2buf   = (float*)alloc((size_t)NN * HID * 4);

    const int* src = ei;
    const int* dst = ei + EE;

    hipMemsetAsync(ws, 0, zero_bytes, stream);
    hipMemsetAsync(nodeList, 0xFF, (size_t)(NBLK * 8) * 4, stream);

    k_pack<<<dim3(100, 4), 256, 0, stream>>>(preW0, preW1, linW0, linW1,
                                             preWt0, preWt1, Lt0, Lt1);
    k_deg<<<EE / 256, 256, 0, stream>>>(dst, deg);
    k_scan<<<1, 1024, 0, stream>>>(deg, offsets, scal, padStart);
    k_fill<<<EE / 256, 256, 0, stream>>>(src, dst, offsets, cursor, csr_src);
    k_scatter<<<(NN + 255) / 256, 256, 0, stream>>>(deg, padStart, binCur, nodeList, slotBin);
    k_wprime<<<dim3(85, NBINS), 256, 0, stream>>>(postW0, postW1, scal, Wp0, Wp1);

    // ---- conv0 (F=16, TFPG=TFPL=80, EP=3, SQ=4, SQX=4) ----
    k_gemm_CP<INDIM, 80, 80, false><<<NN / 16, 256, 0, stream>>>(
        x, preWt0, preb0, nullptr, nullptr, nullptr, Cbuf, Pbuf);
    k_conv<INDIM, 80, 80, 3, 4, 4, true, false><<<NBLK, 256, 0, stream>>>(
        x, Cbuf, Pbuf, offsets, csr_src, nodeList, slotBin, Wp0, postb0, Lt0, linb0,
        nullptr, nullptr, nullptr, h1buf, bnacc0);

    // ---- conv1 (F=50, TFPG=256, TFPL=252, EP=1, SQ=13, SQX=13); BN0 fused ----
    k_gemm_CP<HID, 250, 256, true><<<NN / 16, 256, 0, stream>>>(
        h1buf, preWt1, preb1, bnacc0, gamma0, beta0, Cbuf, Pbuf);
    k_conv<HID, 256, 252, 1, 13, 13, false, true><<<NBLK, 256, 0, stream>>>(
        h1buf, Cbuf, Pbuf, offsets, csr_src, nodeList, slotBin, Wp1, postb1, Lt1, linb1,
        bnacc0, gamma0, beta0, h2buf, bnacc1);

    // ---- BN1+ReLU fused into pooling + head ----
    k_head<<<NGROUPS, 64, 0, stream>>>(h2buf, batch, bnacc1, gamma1, beta1,
                                       mW1, mb1, mW2, mb2, mW3, mb3, out);
}

// Round 12
// 325.885 us; speedup vs baseline: 1.3161x; 1.1241x over previous
//
#include <hip/hip_runtime.h>
#include <math.h>
#include <float.h>

#define NN 20000
#define EE 320000
#define INDIM 16
#define HID 50
#define TW 5
#define FO 10
#define NGROUPS 64
#define NBINS 64
#define NBLK 2556   // (NN + NBINS*7)/8 rounded up

typedef float f4 __attribute__((ext_vector_type(4)));
typedef float f2 __attribute__((ext_vector_type(2)));
typedef _Float16 h4 __attribute__((ext_vector_type(4)));

__device__ inline f4 f4_min(f4 a, f4 b) {
    f4 r; r.x = fminf(a.x, b.x); r.y = fminf(a.y, b.y);
    r.z = fminf(a.z, b.z); r.w = fminf(a.w, b.w); return r;
}
__device__ inline f4 f4_max(f4 a, f4 b) {
    f4 r; r.x = fmaxf(a.x, b.x); r.y = fmaxf(a.y, b.y);
    r.z = fmaxf(a.z, b.z); r.w = fmaxf(a.w, b.w); return r;
}
__device__ inline f4 h2f(h4 h) {
    f4 r; r.x = (float)h.x; r.y = (float)h.y; r.z = (float)h.z; r.w = (float)h.w; return r;
}
__device__ inline float sh3sum(float v, int g0, int G_) {
    return v + __shfl(v, g0 + G_, 64) + __shfl(v, g0 + 2 * G_, 64);
}
__device__ inline float sh3min(float v, int g0, int G_) {
    return fminf(fminf(v, __shfl(v, g0 + G_, 64)), __shfl(v, g0 + 2 * G_, 64));
}
__device__ inline float sh3max(float v, int g0, int G_) {
    return fmaxf(fmaxf(v, __shfl(v, g0 + G_, 64)), __shfl(v, g0 + 2 * G_, 64));
}
__device__ inline void acc4(float& acc, f4 w, float a0, float a1, float a2, float a3) {
    acc += w.x * a0; acc += w.y * a1; acc += w.z * a2; acc += w.w * a3;
}
#define STAT(a) { S += (a); S2 += (a) * (a); MN = f4_min(MN, (a)); MX = f4_max(MX, (a)); }

// ---------- CSR build ----------
__global__ void k_deg(const int* __restrict__ dst, int* __restrict__ deg) {
    int e = blockIdx.x * 256 + threadIdx.x;
    if (e < EE) atomicAdd(&deg[dst[e]], 1);
}

// degrees -> offsets, avg_log, degree histogram -> padded bin starts -> node scatter
__global__ void k_scan(const int* __restrict__ deg, int* __restrict__ offsets,
                       float* __restrict__ scal, int* __restrict__ nodeList) {
    __shared__ int part[1024];
    __shared__ float fred[1024];
    __shared__ int lhist[NBINS];
    __shared__ int spad[NBINS];
    __shared__ int lcur[NBINS];
    const int CH = 20;
    int tid = threadIdx.x;
    if (tid < NBINS) { lhist[tid] = 0; lcur[tid] = 0; }
    __syncthreads();
    int base = tid * CH;
    int loc[CH];
    int s = 0; float fs = 0.f;
    for (int c = 0; c < CH; ++c) {
        int idx = base + c;
        int v = (idx < NN) ? deg[idx] : 0;
        loc[c] = s; s += v;
        if (idx < NN) {
            fs += logf((float)v + 1.0f);
            atomicAdd(&lhist[min(v, NBINS - 1)], 1);
        }
    }
    part[tid] = s; fred[tid] = fs; __syncthreads();
    for (int off = 1; off < 1024; off <<= 1) {
        int v = (tid >= off) ? part[tid - off] : 0;
        __syncthreads();
        part[tid] += v;
        __syncthreads();
    }
    int pre = (tid > 0) ? part[tid - 1] : 0;
    for (int c = 0; c < CH; ++c) {
        int idx = base + c;
        if (idx < NN) offsets[idx] = pre + loc[c];
    }
    if (tid == 0) offsets[NN] = part[1023];
    for (int off = 512; off > 0; off >>= 1) {
        if (tid < off) fred[tid] += fred[tid + off];
        __syncthreads();
    }
    if (tid == 0) {
        scal[0] = fred[0] / (float)NN;
        int acc = 0;
        for (int b = 0; b < NBINS; ++b) {
            spad[b] = acc;
            acc += (lhist[b] + 7) & ~7;
        }
    }
    __syncthreads();
    for (int c = 0; c < CH; ++c) {
        int idx = base + c;
        if (idx < NN) {
            int bin = min(deg[idx], NBINS - 1);
            int pos = spad[bin] + atomicAdd(&lcur[bin], 1);
            nodeList[pos] = idx;
        }
    }
}

__global__ void k_fill(const int* __restrict__ src, const int* __restrict__ dst,
                       const int* __restrict__ offsets, int* __restrict__ cursor,
                       int* __restrict__ csr_src) {
    int e = blockIdx.x * 256 + threadIdx.x;
    if (e < EE) {
        int d = dst[e];
        int pos = offsets[d] + atomicAdd(&cursor[d], 1);
        csr_src[pos] = src[e];
    }
}

// ---------- build combined per-degree post weights W' = Wi + amp*Wa + ia*Wt ----------
__global__ void k_wprime(const float* __restrict__ postW0, const float* __restrict__ postW1,
                         const float* __restrict__ scal,
                         float* __restrict__ Wp0, float* __restrict__ Wp1) {
    int bin = blockIdx.y;
    float degf = fmaxf((float)bin, 1.f);
    float amp = logf(degf + 1.f) / scal[0];
    float ia = 1.f / amp;
    int x = blockIdx.x, t = threadIdx.x;
    int k = t >> 2, j = t & 3;
    if (x < 65) {
        int sq = x;
        int seg = sq / 13, q = sq % 13, f = q * 4 + j;
        float v = 0.f;
        if (f < 50 && k < 50) {
            if (seg == 0) v = postW1[k * 650 + f];
            else {
                int s = seg - 1;
                v = postW1[k * 650 + (1 + s) * 50 + f]
                  + amp * postW1[k * 650 + (5 + s) * 50 + f]
                  + ia * postW1[k * 650 + (9 + s) * 50 + f];
            }
        }
        Wp1[((size_t)bin * 65 + sq) * 256 + t] = v;
    } else {
        int sq = x - 65;  // 0..19
        int seg, f;
        if (sq < 4) { seg = 0; f = sq * 4 + j; }
        else { seg = 1 + (sq - 4) / 4; f = ((sq - 4) % 4) * 4 + j; }
        float v = 0.f;
        if (k < 50) {
            if (seg == 0) v = postW0[k * 208 + f];
            else {
                int s = seg - 1;
                v = postW0[k * 208 + (1 + s) * 16 + f]
                  + amp * postW0[k * 208 + (5 + s) * 16 + f]
                  + ia * postW0[k * 208 + (9 + s) * 16 + f];
            }
        }
        Wp0[((size_t)bin * 20 + sq) * 256 + t] = v;
    }
}

// ---------- pack preW transposed + lin transposed ----------
__global__ void k_pack(const float* __restrict__ preW0, const float* __restrict__ preW1,
                       const float* __restrict__ linW0, const float* __restrict__ linW1,
                       float* __restrict__ preWt0, float* __restrict__ preWt1,
                       float* __restrict__ Lt0, float* __restrict__ Lt1) {
    int idx = blockIdx.x * 256 + threadIdx.x;
    int job = blockIdx.y;
    int q = idx >> 8, k = (idx >> 2) & 63, j = idx & 3;
    switch (job) {
    case 0:
        if (idx < 32 * 80) { int c = idx / 80, r = idx % 80; preWt0[idx] = preW0[r * 32 + c]; }
        break;
    case 1:
        if (idx < 100 * 256) { int c = idx / 256, r = idx % 256; preWt1[idx] = (r < 250) ? preW1[r * 100 + c] : 0.f; }
        break;
    case 2:
        if (idx < 13 * 256) { int f = q * 4 + j; Lt0[idx] = (f < 50 && k < HID) ? linW0[k * 50 + f] : 0.f; }
        break;
    case 3:
        if (idx < 13 * 256) { int f = q * 4 + j; Lt1[idx] = (f < 50 && k < HID) ? linW1[k * 50 + f] : 0.f; }
        break;
    }
}

// ---------- C = x@WL^T + b (fp32), P = x@WR^T (fp16); optional fused BN+ReLU ----------
template <int F, int TF, int TFP, int NODES, bool BN>
__global__ __launch_bounds__(256, 2) void k_gemm_CP(
    const float* __restrict__ x, const float* __restrict__ preWt,
    const float* __restrict__ b,
    const float* __restrict__ bnacc, const float* __restrict__ gam,
    const float* __restrict__ bet,
    float* __restrict__ C, _Float16* __restrict__ P) {
    __shared__ float xs[NODES * F];
    int tid = threadIdx.x;
    int base = blockIdx.x * NODES;
    for (int idx = tid; idx < NODES * F; idx += 256) {
        float v = x[(size_t)base * F + idx];
        if (BN) {
            int c = idx % F;
            float mu = bnacc[c] * (1.f / NN);
            float var = bnacc[64 + c] * (1.f / NN) - mu * mu;
            v = fmaxf(gam[c] * (v - mu) * rsqrtf(var + 1e-5f) + bet[c], 0.f);
        }
        xs[idx] = v;
    }
    __syncthreads();
    if (tid < TF) {
        float accC[NODES], accP[NODES];
#pragma unroll
        for (int n = 0; n < NODES; ++n) { accC[n] = 0.f; accP[n] = 0.f; }
        for (int f = 0; f < F; ++f) {
            float wl = preWt[f * TFP + tid];
            float wr = preWt[(F + f) * TFP + tid];
#pragma unroll
            for (int n = 0; n < NODES; ++n) {
                float xv = xs[n * F + f];
                accC[n] += xv * wl;
                accP[n] += xv * wr;
            }
        }
        float bb = b[tid];
#pragma unroll
        for (int n = 0; n < NODES; ++n) {
            C[((size_t)(base + n)) * TFP + tid] = accC[n] + bb;
            P[((size_t)(base + n)) * TFP + tid] = (_Float16)accP[n];
        }
    } else if (tid < TFP) {
#pragma unroll
        for (int n = 0; n < NODES; ++n) {
            C[((size_t)(base + n)) * TFP + tid] = 0.f;
            P[((size_t)(base + n)) * TFP + tid] = (_Float16)0.f;
        }
    }
}

// ---------- fused conv: degree-binned nodes, combined W', deep-MLP fp16 gather + post + lin + BN ----------
// 8 nodes/block (same degree), 4 waves; wave w owns nodes {2w, 2w+1}.
template <int F, int TFPG, int TFPL, int EP, int SQ, int SQX, bool AF4, bool BNIN>
__global__ __launch_bounds__(256, 4) void k_conv(
    const float* __restrict__ xin, const float* __restrict__ C, const _Float16* __restrict__ P,
    const int* __restrict__ offsets, const int* __restrict__ csr,
    const int* __restrict__ nodeList, const int* __restrict__ deg,
    const float* __restrict__ Wp,
    const float* __restrict__ postb, const float* __restrict__ Lt,
    const float* __restrict__ linb,
    const float* __restrict__ bn_in, const float* __restrict__ g_in,
    const float* __restrict__ b_in,
    float* __restrict__ hout, float* __restrict__ bn_out) {
    const int GP = TFPG / 4;
    const int GL = TFPL / 4;
    const int WQ = SQX + 4 * SQ;
    __shared__ __align__(16) float sAgg[8][4][TFPL];
    __shared__ __align__(16) float sX[8][SQX * 4];
    __shared__ __align__(16) float sY[8][52];
    __shared__ float sBN[4][2][64];
    int t = threadIdx.x, w = t >> 6, lane = t & 63;
    int sbase = blockIdx.x * 8;
    int nodeId[2];

    for (int nn = 0; nn < 2; ++nn) {
        int nd = 2 * w + nn;
        int i = nodeList[sbase + nd];
        nodeId[nn] = i;
        if (i < 0) continue;  // wave-uniform
        int beg = offsets[i], end = offsets[i + 1];
        int d = end - beg;
        int g = (EP == 1) ? lane : (lane % GL);
        int e = (EP == 1) ? 0 : (lane / GL);
        bool act = (EP == 1) ? (lane < GL) : (e < EP);
        f4 S = {0.f, 0.f, 0.f, 0.f}, S2 = {0.f, 0.f, 0.f, 0.f};
        f4 MN = {FLT_MAX, FLT_MAX, FLT_MAX, FLT_MAX};
        f4 MX = {-FLT_MAX, -FLT_MAX, -FLT_MAX, -FLT_MAX};
        const h4* __restrict__ Pv = (const h4*)P;
        if (act) {
            if (EP == 1) {
                int j = beg;
                for (; j + 8 <= end; j += 8) {
                    int s0 = csr[j], s1 = csr[j + 1], s2 = csr[j + 2], s3 = csr[j + 3];
                    int s4 = csr[j + 4], s5 = csr[j + 5], s6 = csr[j + 6], s7 = csr[j + 7];
                    f4 a0 = h2f(Pv[(size_t)s0 * GP + g]);
                    f4 a1 = h2f(Pv[(size_t)s1 * GP + g]);
                    f4 a2 = h2f(Pv[(size_t)s2 * GP + g]);
                    f4 a3 = h2f(Pv[(size_t)s3 * GP + g]);
                    f4 a4 = h2f(Pv[(size_t)s4 * GP + g]);
                    f4 a5 = h2f(Pv[(size_t)s5 * GP + g]);
                    f4 a6 = h2f(Pv[(size_t)s6 * GP + g]);
                    f4 a7 = h2f(Pv[(size_t)s7 * GP + g]);
                    STAT(a0) STAT(a1) STAT(a2) STAT(a3)
                    STAT(a4) STAT(a5) STAT(a6) STAT(a7)
                }
                for (; j + 4 <= end; j += 4) {
                    int s0 = csr[j], s1 = csr[j + 1], s2 = csr[j + 2], s3 = csr[j + 3];
                    f4 a0 = h2f(Pv[(size_t)s0 * GP + g]);
                    f4 a1 = h2f(Pv[(size_t)s1 * GP + g]);
                    f4 a2 = h2f(Pv[(size_t)s2 * GP + g]);
                    f4 a3 = h2f(Pv[(size_t)s3 * GP + g]);
                    STAT(a0) STAT(a1) STAT(a2) STAT(a3)
                }
                for (; j < end; ++j) {
                    int s0 = csr[j];
                    f4 a0 = h2f(Pv[(size_t)s0 * GP + g]);
                    STAT(a0)
                }
            } else {
                int j = beg + e;
                for (; j + 3 * EP < end; j += 4 * EP) {
                    int s0 = csr[j], s1 = csr[j + EP], s2 = csr[j + 2 * EP], s3 = csr[j + 3 * EP];
                    f4 a0 = h2f(Pv[(size_t)s0 * GP + g]);
                    f4 a1 = h2f(Pv[(size_t)s1 * GP + g]);
                    f4 a2 = h2f(Pv[(size_t)s2 * GP + g]);
                    f4 a3 = h2f(Pv[(size_t)s3 * GP + g]);
                    STAT(a0) STAT(a1) STAT(a2) STAT(a3)
                }
                for (; j < end; j += EP) {
                    int s0 = csr[j];
                    f4 a0 = h2f(Pv[(size_t)s0 * GP + g]);
                    STAT(a0)
                }
            }
        }
        if (EP == 3) {
            int g0 = lane % GL;
            S.x = sh3sum(S.x, g0, GL); S.y = sh3sum(S.y, g0, GL);
            S.z = sh3sum(S.z, g0, GL); S.w = sh3sum(S.w, g0, GL);
            S2.x = sh3sum(S2.x, g0, GL); S2.y = sh3sum(S2.y, g0, GL);
            S2.z = sh3sum(S2.z, g0, GL); S2.w = sh3sum(S2.w, g0, GL);
            MN.x = sh3min(MN.x, g0, GL); MN.y = sh3min(MN.y, g0, GL);
            MN.z = sh3min(MN.z, g0, GL); MN.w = sh3min(MN.w, g0, GL);
            MX.x = sh3max(MX.x, g0, GL); MX.y = sh3max(MX.y, g0, GL);
            MX.z = sh3max(MX.z, g0, GL); MX.w = sh3max(MX.w, g0, GL);
        }
        if (lane < GL) {
            f4 Cv = ((const f4*)C)[(size_t)i * GP + lane];
            float degf = (float)d;
            float rdegc = 1.0f / fmaxf(degf, 1.0f);
            f4 mean, sq, var, stdv, mnv, mxv;
            mean.x = (degf * Cv.x + S.x) * rdegc; mean.y = (degf * Cv.y + S.y) * rdegc;
            mean.z = (degf * Cv.z + S.z) * rdegc; mean.w = (degf * Cv.w + S.w) * rdegc;
            sq.x = degf * Cv.x * Cv.x + 2.f * Cv.x * S.x + S2.x;
            sq.y = degf * Cv.y * Cv.y + 2.f * Cv.y * S.y + S2.y;
            sq.z = degf * Cv.z * Cv.z + 2.f * Cv.z * S.z + S2.z;
            sq.w = degf * Cv.w * Cv.w + 2.f * Cv.w * S.w + S2.w;
            var.x = sq.x * rdegc - mean.x * mean.x; var.y = sq.y * rdegc - mean.y * mean.y;
            var.z = sq.z * rdegc - mean.z * mean.z; var.w = sq.w * rdegc - mean.w * mean.w;
            stdv.x = sqrtf(fmaxf(var.x, 0.f) + 1e-5f); stdv.y = sqrtf(fmaxf(var.y, 0.f) + 1e-5f);
            stdv.z = sqrtf(fmaxf(var.z, 0.f) + 1e-5f); stdv.w = sqrtf(fmaxf(var.w, 0.f) + 1e-5f);
            if (d > 0) {
                mnv.x = Cv.x + MN.x; mnv.y = Cv.y + MN.y; mnv.z = Cv.z + MN.z; mnv.w = Cv.w + MN.w;
                mxv.x = Cv.x + MX.x; mxv.y = Cv.y + MX.y; mxv.z = Cv.z + MX.z; mxv.w = Cv.w + MX.w;
            } else {
                mnv = (f4){0.f, 0.f, 0.f, 0.f}; mxv = mnv;
            }
            ((f4*)&sAgg[nd][0][0])[lane] = mean;
            ((f4*)&sAgg[nd][1][0])[lane] = mnv;
            ((f4*)&sAgg[nd][2][0])[lane] = mxv;
            ((f4*)&sAgg[nd][3][0])[lane] = stdv;
        }
        if (BNIN) {
            if (lane < F) {
                float hv = xin[(size_t)i * F + lane];
                float mu = bn_in[lane] * (1.f / NN);
                float var = bn_in[64 + lane] * (1.f / NN) - mu * mu;
                sX[nd][lane] = fmaxf(g_in[lane] * (hv - mu) * rsqrtf(var + 1e-5f) + b_in[lane], 0.f);
            } else if (lane < SQX * 4) {
                sX[nd][lane] = 0.f;
            }
        } else {
            if (lane < F) sX[nd][lane] = xin[(size_t)i * F + lane];
            else if (lane < SQX * 4) sX[nd][lane] = 0.f;
        }
    }
    int fn = nodeList[sbase];
    int bin = (fn >= 0) ? min(deg[fn], NBINS - 1) : 0;  // sentinel-safe
    const f4* __restrict__ Wv = (const f4*)(Wp + (size_t)bin * WQ * 256);
    __syncthreads();  // lockstep waves for shared W' stream

    // ---- post-GEMM (combined W'), R=2 ----
    int nd0 = 2 * w, nd1 = 2 * w + 1;
    int kk = (lane < HID) ? lane : (HID - 1);
    int tw = kk / FO;
    float ya = 0.f, yb = 0.f;
#pragma unroll
    for (int q = 0; q < SQX; ++q) {
        f4 wv = Wv[q * 64 + lane];
        f4 a0 = *(const f4*)(&sX[nd0][4 * q]);
        f4 a1 = *(const f4*)(&sX[nd1][4 * q]);
        acc4(ya, wv, a0.x, a0.y, a0.z, a0.w);
        acc4(yb, wv, a1.x, a1.y, a1.z, a1.w);
    }
#pragma unroll
    for (int s = 0; s < 4; ++s) {
        const float* __restrict__ A0 = &sAgg[nd0][s][tw * F];
        const float* __restrict__ A1 = &sAgg[nd1][s][tw * F];
#pragma unroll 4
        for (int q = 0; q < SQ; ++q) {
            f4 wv = Wv[(SQX + s * SQ + q) * 64 + lane];
            float a00, a01, a02, a03, a10, a11, a12, a13;
            if constexpr (AF4) {
                f4 v0 = *(const f4*)(A0 + 4 * q);
                f4 v1 = *(const f4*)(A1 + 4 * q);
                a00 = v0.x; a01 = v0.y; a02 = v0.z; a03 = v0.w;
                a10 = v1.x; a11 = v1.y; a12 = v1.z; a13 = v1.w;
            } else {
                f2 p0 = *(const f2*)(A0 + 4 * q);
                f2 p1 = *(const f2*)(A0 + 4 * q + 2);
                f2 q0 = *(const f2*)(A1 + 4 * q);
                f2 q1 = *(const f2*)(A1 + 4 * q + 2);
                a00 = p0.x; a01 = p0.y; a02 = p1.x; a03 = p1.y;
                a10 = q0.x; a11 = q0.y; a12 = q1.x; a13 = q1.y;
            }
            acc4(ya, wv, a00, a01, a02, a03);
            acc4(yb, wv, a10, a11, a12, a13);
        }
    }
    float pb = postb[kk];
    ya += pb; yb += pb;
    if (lane < HID) { sY[nd0][lane] = ya; sY[nd1][lane] = yb; }
    else if (lane < 52) { sY[nd0][lane] = 0.f; sY[nd1][lane] = 0.f; }
    // wave-private sY: no barrier needed

    // ---- lin ----
    const f4* __restrict__ Lv = (const f4*)Lt;
    float lb = linb[kk];
    float oa = lb, ob = lb;
#pragma unroll
    for (int q = 0; q < 13; ++q) {
        f4 lv = Lv[q * 64 + lane];
        f4 s0 = *(const f4*)(&sY[nd0][4 * q]);
        f4 s1 = *(const f4*)(&sY[nd1][4 * q]);
        acc4(oa, lv, s0.x, s0.y, s0.z, s0.w);
        acc4(ob, lv, s1.x, s1.y, s1.z, s1.w);
    }
    if (lane < HID) {
        if (nodeId[0] >= 0) hout[(size_t)nodeId[0] * HID + lane] = oa;
        if (nodeId[1] >= 0) hout[(size_t)nodeId[1] * HID + lane] = ob;
    }

    // ---- BN partial stats (sentinel-guarded) ----
    float sv = 0.f, sv2 = 0.f;
    if (lane < HID) {
        if (nodeId[0] >= 0) { sv += oa; sv2 += oa * oa; }
        if (nodeId[1] >= 0) { sv += ob; sv2 += ob * ob; }
    }
    sBN[w][0][lane] = sv;
    sBN[w][1][lane] = sv2;
    __syncthreads();
    if (t < 64 && lane < HID) {
        float s = sBN[0][0][lane] + sBN[1][0][lane] + sBN[2][0][lane] + sBN[3][0][lane];
        float s2 = sBN[0][1][lane] + sBN[1][1][lane] + sBN[2][1][lane] + sBN[3][1][lane];
        atomicAdd(&bn_out[lane], s);
        atomicAdd(&bn_out[64 + lane], s2);
    }
}

// ---------- fused bounds + BN+ReLU + pooling + head MLP ----------
__global__ void k_head(const float* __restrict__ h, const int* __restrict__ batch,
                       const float* __restrict__ bnacc, const float* __restrict__ gam,
                       const float* __restrict__ bet,
                       const float* __restrict__ W1, const float* __restrict__ b1,
                       const float* __restrict__ W2, const float* __restrict__ b2,
                       const float* __restrict__ W3, const float* __restrict__ b3,
                       float* __restrict__ out) {
    __shared__ float sp[HID], h1[50], h2[25];
    __shared__ int sbound[2];
    int g = blockIdx.x, tid = threadIdx.x;
    if (tid < 2) {
        int target = g + tid;
        int lo = 0, hi = NN;
        while (lo < hi) {
            int mid = (lo + hi) >> 1;
            if (batch[mid] < target) lo = mid + 1; else hi = mid;
        }
        sbound[tid] = lo;
    }
    __syncthreads();
    int beg = sbound[0], end = sbound[1];
    if (tid < HID) {
        float mu = bnacc[tid] * (1.f / NN);
        float var = bnacc[64 + tid] * (1.f / NN) - mu * mu;
        float sc = gam[tid] * rsqrtf(var + 1e-5f);
        float sh = bet[tid] - mu * sc;
        float s0 = 0.f, s1 = 0.f, s2 = 0.f, s3 = 0.f;
        int n = beg;
        for (; n + 4 <= end; n += 4) {
            s0 += fmaxf(fmaf(h[(size_t)n * HID + tid], sc, sh), 0.f);
            s1 += fmaxf(fmaf(h[(size_t)(n + 1) * HID + tid], sc, sh), 0.f);
            s2 += fmaxf(fmaf(h[(size_t)(n + 2) * HID + tid], sc, sh), 0.f);
            s3 += fmaxf(fmaf(h[(size_t)(n + 3) * HID + tid], sc, sh), 0.f);
        }
        for (; n < end; ++n) s0 += fmaxf(fmaf(h[(size_t)n * HID + tid], sc, sh), 0.f);
        sp[tid] = (s0 + s1 + s2 + s3) / fmaxf((float)(end - beg), 1.0f);
    }
    __syncthreads();
    if (tid < 50) {
        float a = b1[tid];
        for (int k = 0; k < HID; ++k) a += W1[tid * HID + k] * sp[k];
        h1[tid] = fmaxf(a, 0.f);
    }
    __syncthreads();
    if (tid < 25) {
        float a = b2[tid];
        for (int k = 0; k < 50; ++k) a += W2[tid * 50 + k] * h1[k];
        h2[tid] = fmaxf(a, 0.f);
    }
    __syncthreads();
    if (tid == 0) {
        float a = b3[0];
        for (int k = 0; k < 25; ++k) a += W3[k] * h2[k];
        out[g] = a;
    }
}

extern "C" void kernel_launch(void* const* d_in, const int* in_sizes, int n_in,
                              void* d_out, int out_size, void* d_ws, size_t ws_size,
                              hipStream_t stream) {
    const float* x      = (const float*)d_in[0];
    const int*   ei     = (const int*)d_in[1];
    const int*   batch  = (const int*)d_in[2];
    const float* preW0  = (const float*)d_in[3];
    const float* preb0  = (const float*)d_in[4];
    const float* postW0 = (const float*)d_in[5];
    const float* postb0 = (const float*)d_in[6];
    const float* linW0  = (const float*)d_in[7];
    const float* linb0  = (const float*)d_in[8];
    const float* gamma0 = (const float*)d_in[9];
    const float* beta0  = (const float*)d_in[10];
    const float* preW1  = (const float*)d_in[11];
    const float* preb1  = (const float*)d_in[12];
    const float* postW1 = (const float*)d_in[13];
    const float* postb1 = (const float*)d_in[14];
    const float* linW1  = (const float*)d_in[15];
    const float* linb1  = (const float*)d_in[16];
    const float* gamma1 = (const float*)d_in[17];
    const float* beta1  = (const float*)d_in[18];
    const float* mW1    = (const float*)d_in[19];
    const float* mb1    = (const float*)d_in[20];
    const float* mW2    = (const float*)d_in[21];
    const float* mb2    = (const float*)d_in[22];
    const float* mW3    = (const float*)d_in[23];
    const float* mb3    = (const float*)d_in[24];
    float* out = (float*)d_out;
    (void)in_sizes; (void)n_in; (void)out_size; (void)ws_size;

    char* ws = (char*)d_ws;
    size_t off = 0;
    auto alloc = [&](size_t bytes) -> void* {
        void* p = ws + off;
        off += (bytes + 255) & ~(size_t)255;
        return p;
    };
    // zero-region (one memset): deg, cursor, bnacc0/1
    int*   deg     = (int*)alloc((size_t)NN * 4);
    int*   cursor  = (int*)alloc((size_t)NN * 4);
    float* bnacc0  = (float*)alloc(128 * 4);
    float* bnacc1  = (float*)alloc(128 * 4);
    size_t zero_bytes = off;
    int*   nodeList = (int*)alloc((size_t)(NBLK * 8) * 4);
    int*   offsets = (int*)alloc((size_t)(NN + 1) * 4);
    int*   csr_src = (int*)alloc((size_t)EE * 4);
    float* scal    = (float*)alloc(64);
    float* preWt0  = (float*)alloc((size_t)32 * 80 * 4);
    float* preWt1  = (float*)alloc((size_t)100 * 256 * 4);
    float* Lt0     = (float*)alloc((size_t)13 * 256 * 4);
    float* Lt1     = (float*)alloc((size_t)13 * 256 * 4);
    float* Wp0     = (float*)alloc((size_t)NBINS * 20 * 256 * 4);
    float* Wp1     = (float*)alloc((size_t)NBINS * 65 * 256 * 4);
    float* Cbuf    = (float*)alloc((size_t)NN * 256 * 4);
    _Float16* Pbuf = (_Float16*)alloc((size_t)NN * 256 * 2);
    float* h1buf   = (float*)alloc((size_t)NN * HID * 4);
    float* h2buf   = (float*)alloc((size_t)NN * HID * 4);

    const int* src = ei;
    const int* dst = ei + EE;

    hipMemsetAsync(ws, 0, zero_bytes, stream);
    hipMemsetAsync(nodeList, 0xFF, (size_t)(NBLK * 8) * 4, stream);

    k_pack<<<dim3(100, 4), 256, 0, stream>>>(preW0, preW1, linW0, linW1,
                                             preWt0, preWt1, Lt0, Lt1);
    k_deg<<<EE / 256, 256, 0, stream>>>(dst, deg);
    k_scan<<<1, 1024, 0, stream>>>(deg, offsets, scal, nodeList);
    k_fill<<<EE / 256, 256, 0, stream>>>(src, dst, offsets, cursor, csr_src);
    k_wprime<<<dim3(85, NBINS), 256, 0, stream>>>(postW0, postW1, scal, Wp0, Wp1);

    // ---- conv0 (F=16, TFPG=TFPL=80, EP=3, SQ=4, SQX=4) ----
    k_gemm_CP<INDIM, 80, 80, 32, false><<<NN / 32, 256, 0, stream>>>(
        x, preWt0, preb0, nullptr, nullptr, nullptr, Cbuf, Pbuf);
    k_conv<INDIM, 80, 80, 3, 4, 4, true, false><<<NBLK, 256, 0, stream>>>(
        x, Cbuf, Pbuf, offsets, csr_src, nodeList, deg, Wp0, postb0, Lt0, linb0,
        nullptr, nullptr, nullptr, h1buf, bnacc0);

    // ---- conv1 (F=50, TFPG=256, TFPL=252, EP=1, SQ=13, SQX=13); BN0 fused ----
    k_gemm_CP<HID, 250, 256, 32, true><<<NN / 32, 256, 0, stream>>>(
        h1buf, preWt1, preb1, bnacc0, gamma0, beta0, Cbuf, Pbuf);
    k_conv<HID, 256, 252, 1, 13, 13, false, true><<<NBLK, 256, 0, stream>>>(
        h1buf, Cbuf, Pbuf, offsets, csr_src, nodeList, deg, Wp1, postb1, Lt1, linb1,
        bnacc0, gamma0, beta0, h2buf, bnacc1);

    // ---- BN1+ReLU fused into pooling + head ----
    k_head<<<NGROUPS, 64, 0, stream>>>(h2buf, batch, bnacc1, gamma1, beta1,
                                       mW1, mb1, mW2, mb2, mW3, mb3, out);
}